// Round 8
// baseline (815.835 us; speedup 1.0000x reference)
//
#include <hip/hip_runtime.h>
#include <math.h>

#define N_ATOM 10000
#define NEDGE  160000
#define F      128
#define F3     384
#define NB     20
#define NBLK   3
#define PI_F   3.14159265358979323846f

typedef __attribute__((ext_vector_type(8))) short bf16x8;
typedef __attribute__((ext_vector_type(4))) float f32x4;
#define MFMA16(a,b,c) __builtin_amdgcn_mfma_f32_16x16x32_bf16(a,b,c,0,0,0)

__device__ __forceinline__ float silu_f(float x){ return x / (1.0f + __expf(-x)); }
__device__ __forceinline__ short f2b(float f){            // fp32 -> bf16 RNE
  unsigned u = __float_as_uint(f);
  u += 0x7fff + ((u >> 16) & 1);
  return (short)(u >> 16);
}
__device__ __forceinline__ float b2f(short s){
  return __uint_as_float(((unsigned)(unsigned short)s) << 16);
}
__device__ __forceinline__ float blo(unsigned u){ return __uint_as_float(u << 16); }
__device__ __forceinline__ float bhi(unsigned u){ return __uint_as_float(u & 0xffff0000u); }
__device__ __forceinline__ unsigned packb(float a, float b){
  return ((unsigned)(unsigned short)f2b(a)) | (((unsigned)(unsigned short)f2b(b)) << 16);
}

// ---------------------------------------------------------------- weight cast+transpose -> bf16 [N][K]
__global__ __launch_bounds__(256) void k_prep(const float* __restrict__ Wm1, const float* __restrict__ Wm2,
                                              const float* __restrict__ Uw,  const float* __restrict__ Vw,
                                              const float* __restrict__ Wu1, const float* __restrict__ Wu2,
                                              short* __restrict__ wt){
  int idx = blockIdx.x * 256 + threadIdx.x;          // 540672 total
  short* wm1t = wt;                                   // 3*[128][128]
  short* wm2t = wt + 49152;                           // 3*[384][128]
  short* uwt  = wt + 196608;                          // 3*[128][128]
  short* vwt  = wt + 245760;                          // 3*[128][128]
  short* wu1t = wt + 294912;                          // 3*[128][256]
  short* wu2t = wt + 393216;                          // 3*[384][128]
  if (idx < 49152){
    int b = idx >> 14, r = idx & 16383, n = r >> 7, k = r & 127;
    wm1t[idx] = f2b(Wm1[b*16384 + k*128 + n]);
  } else if (idx < 196608){
    int j = idx - 49152;
    int b = j / 49152, r = j % 49152, n = r >> 7, k = r & 127;
    wm2t[j] = f2b(Wm2[b*49152 + k*384 + n]);
  } else if (idx < 245760){
    int j = idx - 196608;
    int b = j >> 14, r = j & 16383, n = r >> 7, k = r & 127;
    uwt[j] = f2b(Uw[b*16384 + k*128 + n]);
  } else if (idx < 294912){
    int j = idx - 245760;
    int b = j >> 14, r = j & 16383, n = r >> 7, k = r & 127;
    vwt[j] = f2b(Vw[b*16384 + k*128 + n]);
  } else if (idx < 393216){
    int j = idx - 294912;
    int b = j >> 15, r = j & 32767, n = r >> 8, k = r & 255;
    wu1t[j] = f2b(Wu1[b*32768 + k*128 + n]);
  } else if (idx < 540672){
    int j = idx - 393216;
    int b = j / 49152, r = j % 49152, n = r >> 7, k = r & 127;
    wu2t[j] = f2b(Wu2[b*49152 + k*384 + n]);
  }
}

// ---------------------------------------------------------------- init: x = z_embed[z], v = 0
__global__ __launch_bounds__(256) void k_init(const float* __restrict__ z_embed,
                                              const int* __restrict__ z,
                                              float* __restrict__ x, float* __restrict__ v){
  int idx = blockIdx.x * 256 + threadIdx.x;
  if (idx < N_ATOM * F){
    int i = idx >> 7, f = idx & 127;
    x[idx] = z_embed[z[i] * F + f];
  }
  if (idx < N_ATOM * 3 * F) v[idx] = 0.0f;
}

// ---------------------------------------------------------------- pack fp32 v -> bf16-pair shadow (per block iter)
__global__ __launch_bounds__(256) void k_packv(const float* __restrict__ v, unsigned* __restrict__ v_b){
  int idx = blockIdx.x * 256 + threadIdx.x;          // grid 7500 exact (10000*192)
  const float* p = v + (size_t)idx * 2;
  v_b[idx] = packb(p[0], p[1]);
}

// ---------------------------------------------------------------- CSR build
__global__ __launch_bounds__(256) void k_hist(const int* __restrict__ ei, int* __restrict__ deg){
  int e = blockIdx.x * 256 + threadIdx.x;
  atomicAdd(&deg[ei[NEDGE + e]], 1);
}

__global__ __launch_bounds__(1024) void k_scan(const int* __restrict__ deg,
                                               int* __restrict__ rowptr, int* __restrict__ cursor){
  __shared__ int part[1024];
  int t = threadIdx.x;
  int base = t * 10;
  int loc[10];
  int s = 0;
  #pragma unroll
  for (int i = 0; i < 10; i++){
    int idx = base + i;
    int d = (idx < N_ATOM) ? deg[idx] : 0;
    loc[i] = s; s += d;
  }
  part[t] = s;
  __syncthreads();
  for (int off = 1; off < 1024; off <<= 1){
    int vp = 0;
    if (t >= off) vp = part[t - off];
    __syncthreads();
    part[t] += vp;
    __syncthreads();
  }
  int offset = (t == 0) ? 0 : part[t - 1];
  #pragma unroll
  for (int i = 0; i < 10; i++){
    int idx = base + i;
    if (idx < N_ATOM){ rowptr[idx] = offset + loc[i]; cursor[idx] = offset + loc[i]; }
  }
  if (t == 1023) rowptr[N_ATOM] = part[1023];
}

__global__ __launch_bounds__(256) void k_slot(const int* __restrict__ ei,
                                              int* __restrict__ cursor, int* __restrict__ slot){
  int e = blockIdx.x * 256 + threadIdx.x;
  int p = atomicAdd(&cursor[ei[NEDGE + e]], 1);
  slot[e] = p;
}

// ---------------------------------------------------------------- edge geometry -> dst-sorted slots
__global__ __launch_bounds__(256) void k_geo(const float* __restrict__ pos,
                                             const int* __restrict__ ei,
                                             const int* __restrict__ slot,
                                             int* __restrict__ srcs,
                                             float* __restrict__ rhs,
                                             float* __restrict__ rbfs,
                                             float* __restrict__ fcs){
  int e = blockIdx.x * 256 + threadIdx.x;
  int s = ei[e], d_ = ei[NEDGE + e];
  int p = slot[e];
  float rx = pos[d_*3+0] - pos[s*3+0];
  float ry = pos[d_*3+1] - pos[s*3+1];
  float rz = pos[d_*3+2] - pos[s*3+2];
  float d  = sqrtf(rx*rx + ry*ry + rz*rz + 1e-8f);
  float inv = 1.0f / d;
  srcs[p] = s;
  rhs[p*3+0] = rx*inv; rhs[p*3+1] = ry*inv; rhs[p*3+2] = rz*inv;
  float fcv = (d < 5.0f) ? 0.5f * (cosf(PI_F * d * 0.2f) + 1.0f) : 0.0f;
  fcs[p] = fcv;
  float base = PI_F * d * 0.2f;
  float sc = inv * fcv;
  #pragma unroll
  for (int k = 0; k < NB; k++){
    rbfs[(size_t)p*NB + k] = sinf(base * (float)(k+1)) * sc;
  }
}

// ---------------------------------------------------------------- MFMA node phi: LN + GEMM1 + silu + GEMM2
// 16 rows/block, 625 blocks (4x parallelism vs prev 157). phi emitted bf16-packed.
__global__ __launch_bounds__(256) void k_node_phi(const float* __restrict__ x,
                                                  unsigned* __restrict__ phi_b,
                                                  const float* __restrict__ ln_g, const float* __restrict__ ln_b,
                                                  const short* __restrict__ Wm1t, const float* __restrict__ bm1,
                                                  const short* __restrict__ Wm2t, const float* __restrict__ bm2){
  __shared__ short xn_s[16*136];
  __shared__ short h_s [16*136];
  __shared__ float mu_s[16], rs_s[16];
  int t = threadIdx.x;
  int row0 = blockIdx.x * 16;

  { // LN stats: 16 threads per row
    int r = t >> 4, q = t & 15;
    const float* xr = x + (size_t)(row0 + r) * F;
    float s = 0.f, ss = 0.f;
    #pragma unroll
    for (int i = 0; i < 8; i++){ float vv = xr[q + 16*i]; s += vv; ss += vv*vv; }
    #pragma unroll
    for (int m = 8; m >= 1; m >>= 1){ s += __shfl_xor(s, m, 64); ss += __shfl_xor(ss, m, 64); }
    if (q == 0){
      float mu = s * (1.0f/F);
      mu_s[r] = mu; rs_s[r] = rsqrtf(ss * (1.0f/F) - mu*mu + 1e-5f);
    }
  }
  __syncthreads();
  #pragma unroll
  for (int i = 0; i < 8; i++){              // xn fill (16*128 = 2048)
    int idx = t + 256*i; int r = idx >> 7, f = idx & 127;
    float vv = x[(size_t)(row0 + r)*F + f];
    xn_s[r*136 + f] = f2b((vv - mu_s[r]) * rs_s[r] * ln_g[f] + ln_b[f]);
  }
  __syncthreads();

  int l = t & 63, w = t >> 6;
  int kof = (l >> 4) * 8;
  int arow = l & 15;

  { // GEMM1: h = silu(xn @ Wm1 + bm1); 8 col-tiles, 2/wave
    bf16x8 af[4];
    #pragma unroll
    for (int ks = 0; ks < 4; ks++) af[ks] = *(const bf16x8*)&xn_s[arow*136 + ks*32 + kof];
    #pragma unroll
    for (int cc = 0; cc < 2; cc++){
      int col = (w*2 + cc)*16 + (l & 15);
      float bb = bm1[col];
      f32x4 acc = {bb, bb, bb, bb};
      #pragma unroll
      for (int ks = 0; ks < 4; ks++){
        bf16x8 bf = *(const bf16x8*)&Wm1t[col*F + ks*32 + kof];
        acc = MFMA16(af[ks], bf, acc);
      }
      #pragma unroll
      for (int i = 0; i < 4; i++) h_s[((l>>4)*4 + i)*136 + col] = f2b(silu_f(acc[i]));
    }
  }
  __syncthreads();
  { // GEMM2: phi = h @ Wm2 + bm2, bf16-pair packed out; 24 col-tiles, 6/wave
    bf16x8 ah[4];
    #pragma unroll
    for (int ks = 0; ks < 4; ks++) ah[ks] = *(const bf16x8*)&h_s[arow*136 + ks*32 + kof];
    #pragma unroll
    for (int cc = 0; cc < 6; cc++){
      int col = (w*6 + cc)*16 + (l & 15);
      float bb = bm2[col];
      f32x4 acc = {bb, bb, bb, bb};
      #pragma unroll
      for (int ks = 0; ks < 4; ks++){
        bf16x8 bf = *(const bf16x8*)&Wm2t[col*F + ks*32 + kof];
        acc = MFMA16(ah[ks], bf, acc);
      }
      #pragma unroll
      for (int i = 0; i < 4; i++){
        float val = acc[i];
        float oth = __shfl_xor(val, 1, 64);     // partner holds col^1
        if (!(l & 1)){                          // even lane packs (col, col+1)
          int row = row0 + (l>>4)*4 + i;
          int seg = col >> 7, cin = col & 127;
          phi_b[(size_t)row*192 + seg*64 + (cin >> 1)] = packb(val, oth);
        }
      }
    }
  }
}

// ---------------------------------------------------------------- OWNER-WAVE edge gather (bf16-packed payloads)
// one wave per dst node; lane owns feature pair (2*lane, 2*lane+1); writes dv (delta) + x.
__global__ __launch_bounds__(256) void k_edge_g(const int* __restrict__ rowptr,
                                                const int* __restrict__ srcs,
                                                const float* __restrict__ rbfs,
                                                const float* __restrict__ rhs,
                                                const float* __restrict__ fcs,
                                                const unsigned* __restrict__ phi_b,
                                                const unsigned* __restrict__ v_b,
                                                const float* __restrict__ Wrbf,
                                                const float* __restrict__ brbf,
                                                float* __restrict__ x,
                                                float* __restrict__ dv){
  __shared__ float W[NB * F3];                       // fp32: exact Wf
  int t = threadIdx.x;
  #pragma unroll
  for (int i = 0; i < (NB*F3)/256; i++) W[t + 256*i] = Wrbf[t + 256*i];
  __syncthreads();

  int wid = t >> 6, lane = t & 63;
  int n = blockIdx.x * 4 + wid;                      // 2500 blocks * 4 waves
  int f0 = 2 * lane;                                 // feature pair (f0, f0+1)
  int r0 = rowptr[n], r1 = rowptr[n+1];

  float2 bs  = *(const float2*)&brbf[f0];
  float2 bvv = *(const float2*)&brbf[F + f0];
  float2 bvs = *(const float2*)&brbf[2*F + f0];

  float ax0=0.f, ax1=0.f;
  float av00=0.f, av01=0.f, av10=0.f, av11=0.f, av20=0.f, av21=0.f;

  for (int j = r0; j < r1; ++j){
    int s = srcs[j];
    // issue gathers early; latency hides under the 20-k W dot
    const unsigned* pb = phi_b + (size_t)s * 192 + lane;
    const unsigned* vb = v_b   + (size_t)s * 192 + lane;
    unsigned p0 = pb[0], p1 = pb[64], p2 = pb[128];
    unsigned q0 = vb[0], q1 = vb[64], q2 = vb[128];
    float fcv = fcs[j];
    float rh0 = rhs[j*3+0], rh1 = rhs[j*3+1], rh2 = rhs[j*3+2];
    const float* rb = rbfs + (size_t)j * NB;
    float ws0=0.f, ws1=0.f, wv0=0.f, wv1=0.f, wq0=0.f, wq1=0.f;
    #pragma unroll
    for (int k = 0; k < NB; k++){
      float r = rb[k];                               // broadcast load
      float2 w0 = *(const float2*)&W[k*F3 + f0];
      float2 w1 = *(const float2*)&W[k*F3 + F + f0];
      float2 w2 = *(const float2*)&W[k*F3 + 2*F + f0];
      ws0 += r*w0.x; ws1 += r*w0.y;
      wv0 += r*w1.x; wv1 += r*w1.y;
      wq0 += r*w2.x; wq1 += r*w2.y;
    }
    float ms0  = blo(p0) * (ws0 + bs.x *fcv);
    float ms1  = bhi(p0) * (ws1 + bs.y *fcv);
    float mvv0 = blo(p1) * (wv0 + bvv.x*fcv);
    float mvv1 = bhi(p1) * (wv1 + bvv.y*fcv);
    float mvs0 = blo(p2) * (wq0 + bvs.x*fcv);
    float mvs1 = bhi(p2) * (wq1 + bvs.y*fcv);
    ax0 += ms0; ax1 += ms1;
    av00 += mvv0*blo(q0) + mvs0*rh0;  av01 += mvv1*bhi(q0) + mvs1*rh0;
    av10 += mvv0*blo(q1) + mvs0*rh1;  av11 += mvv1*bhi(q1) + mvs1*rh1;
    av20 += mvv0*blo(q2) + mvs0*rh2;  av21 += mvv1*bhi(q2) + mvs1*rh2;
  }

  float2* xp = (float2*)&x[(size_t)n*F + f0];
  float2 xv = *xp; xv.x += ax0; xv.y += ax1; *xp = xv;
  size_t vb0 = (size_t)n * 3 * F;
  *(float2*)&dv[vb0 + f0]       = make_float2(av00, av01);
  *(float2*)&dv[vb0 + F + f0]   = make_float2(av10, av11);
  *(float2*)&dv[vb0 + 2*F + f0] = make_float2(av20, av21);
}

// ---------------------------------------------------------------- MFMA node update: Uv/Vv, LN2, gated MLP, x/v update
// 16 nodes (48 v-rows)/block, 625 blocks. vnew = v + dv formed in fp32 here.
__global__ __launch_bounds__(256) void k_node_upd(float* __restrict__ x, float* __restrict__ v,
                                                  const float* __restrict__ dv,
                                                  const short* __restrict__ Uwt, const short* __restrict__ Vwt,
                                                  const float* __restrict__ ln2_g, const float* __restrict__ ln2_b,
                                                  const short* __restrict__ Wu1t, const float* __restrict__ bu1,
                                                  const short* __restrict__ Wu2t, const float* __restrict__ bu2){
  __shared__ __align__(16) char smem[59776];
  short* vt   = (short*)smem;                          // [48][136] bf16 (v+dv)
  short* Uv_s = (short*)(smem + 13056);                // [48][136]
  char*  R    = smem + 26112;                          // union region (24576 B)
  short* Vv_s = (short*)R;                             // [48][136] (phases 1-2)
  short* ab   = (short*)(R + 13056);                   // [16][264] concat A (phases 2-3)
  float* a_s  = (float*)R;                             // [16][384] (phases 4-5)
  short* h2   = (short*)(smem + 50688);                // [16][136]
  short* duv  = (short*)(smem + 55040);                // [16][136]
  float* mu_s = (float*)(smem + 59392);                // [16]
  float* rs_s = mu_s + 16;

  int t = threadIdx.x;
  int n0 = blockIdx.x * 16;

  { // LN2 stats on x: 16 threads/row
    int r = t >> 4, q = t & 15;
    const float* xr = x + (size_t)(n0 + r) * F;
    float s = 0.f, ss = 0.f;
    #pragma unroll
    for (int i = 0; i < 8; i++){ float vv = xr[q + 16*i]; s += vv; ss += vv*vv; }
    #pragma unroll
    for (int m = 8; m >= 1; m >>= 1){ s += __shfl_xor(s, m, 64); ss += __shfl_xor(ss, m, 64); }
    if (q == 0){ float mu = s*(1.0f/F); mu_s[r] = mu; rs_s[r] = rsqrtf(ss*(1.0f/F) - mu*mu + 1e-5f); }
  }
  #pragma unroll
  for (int i = 0; i < 24; i++){               // (v+dv) -> bf16 LDS (48*128 = 6144)
    int idx = t + 256*i;
    size_t g = (size_t)n0*3*F + idx;
    vt[(idx >> 7)*136 + (idx & 127)] = f2b(v[g] + dv[g]);
  }
  __syncthreads();

  int l = t & 63, w = t >> 6;
  int kof = (l >> 4) * 8;

  { // Uv/Vv GEMMs: 12 jobs (3 rowtiles x {U,V} x 2 col-halves), 3 per wave
    #pragma unroll
    for (int jj = 0; jj < 3; jj++){
      int job = w*3 + jj;
      int rt = job >> 2, rem = job & 3, mat = rem >> 1, ch = rem & 1;
      const short* Bt = mat ? Vwt : Uwt;
      short* Out = mat ? Vv_s : Uv_s;
      bf16x8 af[4];
      #pragma unroll
      for (int ks = 0; ks < 4; ks++) af[ks] = *(const bf16x8*)&vt[(rt*16 + (l&15))*136 + ks*32 + kof];
      #pragma unroll
      for (int ct = 0; ct < 4; ct++){
        int col = ch*64 + ct*16 + (l & 15);
        f32x4 acc = {0.f, 0.f, 0.f, 0.f};
        #pragma unroll
        for (int ks = 0; ks < 4; ks++){
          bf16x8 bf = *(const bf16x8*)&Bt[col*F + ks*32 + kof];
          acc = MFMA16(af[ks], bf, acc);
        }
        #pragma unroll
        for (int i = 0; i < 4; i++) Out[(rt*16 + (l>>4)*4 + i)*136 + col] = f2b(acc[i]);
      }
    }
  }
  __syncthreads();

  { // xn2, vnorm, duv
    #pragma unroll
    for (int i = 0; i < 8; i++){
      int idx = t + 256*i; int n = idx >> 7, f = idx & 127;
      float xv = x[(size_t)(n0 + n)*F + f];
      ab[n*264 + f] = f2b((xv - mu_s[n]) * rs_s[n] * ln2_g[f] + ln2_b[f]);
      float v0 = b2f(Vv_s[(3*n+0)*136 + f]), v1 = b2f(Vv_s[(3*n+1)*136 + f]), v2 = b2f(Vv_s[(3*n+2)*136 + f]);
      float u0 = b2f(Uv_s[(3*n+0)*136 + f]), u1 = b2f(Uv_s[(3*n+1)*136 + f]), u2 = b2f(Uv_s[(3*n+2)*136 + f]);
      ab[n*264 + 128 + f] = f2b(sqrtf(v0*v0 + v1*v1 + v2*v2 + 1e-8f));
      duv[n*136 + f] = f2b(u0*v0 + u1*v1 + u2*v2);
    }
  }
  __syncthreads();

  { // Wu1 GEMM (K=256) + silu -> h2; 8 col-tiles, 2/wave
    bf16x8 af[8];
    #pragma unroll
    for (int ks = 0; ks < 8; ks++) af[ks] = *(const bf16x8*)&ab[(l&15)*264 + ks*32 + kof];
    #pragma unroll
    for (int cc = 0; cc < 2; cc++){
      int col = (w*2 + cc)*16 + (l & 15);
      float bb = bu1[col];
      f32x4 acc = {bb, bb, bb, bb};
      #pragma unroll
      for (int ks = 0; ks < 8; ks++){
        bf16x8 bf = *(const bf16x8*)&Wu1t[col*256 + ks*32 + kof];
        acc = MFMA16(af[ks], bf, acc);
      }
      #pragma unroll
      for (int i = 0; i < 4; i++) h2[((l>>4)*4 + i)*136 + col] = f2b(silu_f(acc[i]));
    }
  }
  __syncthreads();

  { // Wu2 GEMM -> a_s fp32; 24 col-tiles, 6/wave
    bf16x8 af[4];
    #pragma unroll
    for (int ks = 0; ks < 4; ks++) af[ks] = *(const bf16x8*)&h2[(l&15)*136 + ks*32 + kof];
    #pragma unroll
    for (int cc = 0; cc < 6; cc++){
      int col = (w*6 + cc)*16 + (l & 15);
      float bb = bu2[col];
      f32x4 acc = {bb, bb, bb, bb};
      #pragma unroll
      for (int ks = 0; ks < 4; ks++){
        bf16x8 bf = *(const bf16x8*)&Wu2t[col*F + ks*32 + kof];
        acc = MFMA16(af[ks], bf, acc);
      }
      #pragma unroll
      for (int i = 0; i < 4; i++) a_s[((l>>4)*4 + i)*384 + col] = acc[i];
    }
  }
  __syncthreads();

  { // final updates: fp32 state
    #pragma unroll
    for (int i = 0; i < 8; i++){
      int idx = t + 256*i; int n = idx >> 7, f = idx & 127;
      float avv = a_s[n*384 + f], asv = a_s[n*384 + 128 + f], ass = a_s[n*384 + 256 + f];
      size_t xr_ = (size_t)(n0 + n)*F + f;
      x[xr_] = x[xr_] + asv * b2f(duv[n*136 + f]) + ass;
      #pragma unroll
      for (int c = 0; c < 3; c++){
        size_t vr = (size_t)((n0 + n)*3 + c)*F + f;
        v[vr] = v[vr] + dv[vr] + avv * b2f(Uv_s[(3*n + c)*136 + f]);
      }
    }
  }
}

// ---------------------------------------------------------------- output head + global sum
__global__ __launch_bounds__(256) void k_out(const float* __restrict__ x,
                                             const float* __restrict__ Wo1, const float* __restrict__ bo1,
                                             const float* __restrict__ Wo2, const float* __restrict__ bo2,
                                             float* __restrict__ out){
  __shared__ float xl[8][F];
  __shared__ float hl[8][F];
  __shared__ float er[8];
  int t = threadIdx.x; int n0 = blockIdx.x * 8;
  #pragma unroll
  for (int i = 0; i < 4; i++){ int idx = t + 256*i; ((float*)xl)[idx] = x[(size_t)n0*F + idx]; }
  __syncthreads();
  { int g = t & 127, grp = t >> 7;
    float acc[4];
    #pragma unroll
    for (int n = 0; n < 4; n++) acc[n] = bo1[g];
    for (int k = 0; k < F; k++){
      float w = Wo1[k*F + g];
      #pragma unroll
      for (int n = 0; n < 4; n++) acc[n] += xl[grp*4+n][k] * w;
    }
    #pragma unroll
    for (int n = 0; n < 4; n++) hl[grp*4+n][g] = silu_f(acc[n]);
  }
  __syncthreads();
  { int r = t >> 5, lq = t & 31;
    float s = 0.f;
    #pragma unroll
    for (int i = 0; i < 4; i++) s += hl[r][lq + 32*i] * Wo2[lq + 32*i];
    #pragma unroll
    for (int m = 16; m >= 1; m >>= 1) s += __shfl_xor(s, m, 64);
    if (lq == 0) er[r] = s + bo2[0];
  }
  __syncthreads();
  if (t == 0){
    float s = 0.f;
    #pragma unroll
    for (int r = 0; r < 8; r++) s += er[r];
    unsafeAtomicAdd(out, s);
  }
}

// ----------------------------------------------------------------
extern "C" void kernel_launch(void* const* d_in, const int* in_sizes, int n_in,
                              void* d_out, int out_size, void* d_ws, size_t ws_size,
                              hipStream_t stream){
  const float* pos     = (const float*)d_in[0];
  const int*   z       = (const int*)  d_in[1];
  const int*   ei      = (const int*)  d_in[2];
  const float* z_embed = (const float*)d_in[3];
  const float* Wrbf    = (const float*)d_in[4];
  const float* brbf    = (const float*)d_in[5];
  const float* ln_g    = (const float*)d_in[6];
  const float* ln_b    = (const float*)d_in[7];
  const float* Wm1     = (const float*)d_in[8];
  const float* bm1     = (const float*)d_in[9];
  const float* Wm2     = (const float*)d_in[10];
  const float* bm2     = (const float*)d_in[11];
  const float* Uw      = (const float*)d_in[12];
  const float* Vw      = (const float*)d_in[13];
  const float* ln2_g   = (const float*)d_in[14];
  const float* ln2_b   = (const float*)d_in[15];
  const float* Wu1     = (const float*)d_in[16];
  const float* bu1     = (const float*)d_in[17];
  const float* Wu2     = (const float*)d_in[18];
  const float* bu2     = (const float*)d_in[19];
  const float* Wo1     = (const float*)d_in[20];
  const float* bo1     = (const float*)d_in[21];
  const float* Wo2     = (const float*)d_in[22];
  const float* bo2     = (const float*)d_in[23];

  float* ws = (float*)d_ws;
  size_t o = 0;
  float*    x     = ws + o; o += (size_t)N_ATOM * F;
  float*    v     = ws + o; o += (size_t)N_ATOM * 3 * F;
  float*    dv    = ws + o; o += (size_t)N_ATOM * 3 * F;
  unsigned* phi_b = (unsigned*)(ws + o); o += (size_t)N_ATOM * 192;
  unsigned* v_b   = (unsigned*)(ws + o); o += (size_t)N_ATOM * 192;
  float*    rhs   = ws + o; o += (size_t)NEDGE * 3;
  float*    rbfs  = ws + o; o += (size_t)NEDGE * NB;
  float*    fcs   = ws + o; o += (size_t)NEDGE;
  int*      rowptr= (int*)(ws + o); o += N_ATOM + 16;
  int*      srcs  = (int*)(ws + o); o += NEDGE;
  short*    wt    = (short*)(ws + o); o += 270336 + 8;   // 540672 bf16 weights
  // transient CSR-build arrays alias the dv region (dv first written in
  // k_edge_g, strictly after k_slot/k_geo complete)
  int* deg    = (int*)dv;
  int* cursor = deg + 10240;
  int* slot   = cursor + 10240;

  short* wm1t = wt;
  short* wm2t = wt + 49152;
  short* uwt  = wt + 196608;
  short* vwt  = wt + 245760;
  short* wu1t = wt + 294912;
  short* wu2t = wt + 393216;

  hipMemsetAsync(d_out, 0, sizeof(float), stream);
  hipMemsetAsync(deg, 0, N_ATOM * sizeof(int), stream);
  k_prep<<<2112, 256, 0, stream>>>(Wm1, Wm2, Uw, Vw, Wu1, Wu2, wt);
  k_hist<<<NEDGE/256, 256, 0, stream>>>(ei, deg);
  k_scan<<<1, 1024, 0, stream>>>(deg, rowptr, cursor);
  k_slot<<<NEDGE/256, 256, 0, stream>>>(ei, cursor, slot);
  k_geo <<<NEDGE/256, 256, 0, stream>>>(pos, ei, slot, srcs, rhs, rbfs, fcs);
  k_init<<<(N_ATOM*3*F + 255)/256, 256, 0, stream>>>(z_embed, z, x, v);

  for (int b = 0; b < NBLK; b++){
    k_node_phi<<<N_ATOM/16, 256, 0, stream>>>(x, phi_b,
        ln_g + b*F, ln_b + b*F, wm1t + b*16384, bm1 + b*F,
        wm2t + b*49152, bm2 + b*F3);
    k_packv<<<(N_ATOM*192)/256, 256, 0, stream>>>(v, v_b);
    k_edge_g<<<N_ATOM/4, 256, 0, stream>>>(rowptr, srcs, rbfs, rhs, fcs,
        phi_b, v_b, Wrbf + (size_t)b*NB*F3, brbf + b*F3, x, dv);
    k_node_upd<<<N_ATOM/16, 256, 0, stream>>>(x, v, dv,
        uwt + b*16384, vwt + b*16384,
        ln2_g + b*F, ln2_b + b*F,
        wu1t + b*32768, bu1 + b*F,
        wu2t + b*49152, bu2 + b*F3);
  }
  k_out<<<N_ATOM/8, 256, 0, stream>>>(x, Wo1, bo1, Wo2, bo2, (float*)d_out);
}

// Round 13
// 712.659 us; speedup vs baseline: 1.1448x; 1.1448x over previous
//
#include <hip/hip_runtime.h>
#include <math.h>

#define N_ATOM 10000
#define NEDGE  160000
#define F      128
#define F3     384
#define NB     20
#define NBLK   3
#define PI_F   3.14159265358979323846f

typedef __attribute__((ext_vector_type(8))) short bf16x8;
typedef __attribute__((ext_vector_type(4))) float f32x4;
#define MFMA16(a,b,c) __builtin_amdgcn_mfma_f32_16x16x32_bf16(a,b,c,0,0,0)

__device__ __forceinline__ float silu_f(float x){ return x / (1.0f + __expf(-x)); }
__device__ __forceinline__ short f2b(float f){            // fp32 -> bf16 RNE
  unsigned u = __float_as_uint(f);
  u += 0x7fff + ((u >> 16) & 1);
  return (short)(u >> 16);
}
__device__ __forceinline__ float b2f(short s){
  return __uint_as_float(((unsigned)(unsigned short)s) << 16);
}

// ---------------------------------------------------------------- weight cast+transpose -> bf16 [N][K]
__global__ __launch_bounds__(256) void k_prep(const float* __restrict__ Wm1, const float* __restrict__ Wm2,
                                              const float* __restrict__ Uw,  const float* __restrict__ Vw,
                                              const float* __restrict__ Wu1, const float* __restrict__ Wu2,
                                              short* __restrict__ wt){
  int idx = blockIdx.x * 256 + threadIdx.x;          // 540672 total
  short* wm1t = wt;                                   // 3*[128][128]
  short* wm2t = wt + 49152;                           // 3*[384][128]
  short* uwt  = wt + 196608;                          // 3*[128][128]
  short* vwt  = wt + 245760;                          // 3*[128][128]
  short* wu1t = wt + 294912;                          // 3*[128][256]
  short* wu2t = wt + 393216;                          // 3*[384][128]
  if (idx < 49152){
    int b = idx >> 14, r = idx & 16383, n = r >> 7, k = r & 127;
    wm1t[idx] = f2b(Wm1[b*16384 + k*128 + n]);
  } else if (idx < 196608){
    int j = idx - 49152;
    int b = j / 49152, r = j % 49152, n = r >> 7, k = r & 127;
    wm2t[j] = f2b(Wm2[b*49152 + k*384 + n]);
  } else if (idx < 245760){
    int j = idx - 196608;
    int b = j >> 14, r = j & 16383, n = r >> 7, k = r & 127;
    uwt[j] = f2b(Uw[b*16384 + k*128 + n]);
  } else if (idx < 294912){
    int j = idx - 245760;
    int b = j >> 14, r = j & 16383, n = r >> 7, k = r & 127;
    vwt[j] = f2b(Vw[b*16384 + k*128 + n]);
  } else if (idx < 393216){
    int j = idx - 294912;
    int b = j >> 15, r = j & 32767, n = r >> 8, k = r & 255;
    wu1t[j] = f2b(Wu1[b*32768 + k*128 + n]);
  } else if (idx < 540672){
    int j = idx - 393216;
    int b = j / 49152, r = j % 49152, n = r >> 7, k = r & 127;
    wu2t[j] = f2b(Wu2[b*49152 + k*384 + n]);
  }
}

// ---------------------------------------------------------------- init: x = z_embed[z], v = 0
__global__ __launch_bounds__(256) void k_init(const float* __restrict__ z_embed,
                                              const int* __restrict__ z,
                                              float* __restrict__ x, float* __restrict__ v){
  int idx = blockIdx.x * 256 + threadIdx.x;
  if (idx < N_ATOM * F){
    int i = idx >> 7, f = idx & 127;
    x[idx] = z_embed[z[i] * F + f];
  }
  if (idx < N_ATOM * 3 * F) v[idx] = 0.0f;
}

// ---------------------------------------------------------------- CSR build
__global__ __launch_bounds__(256) void k_hist(const int* __restrict__ ei, int* __restrict__ deg){
  int e = blockIdx.x * 256 + threadIdx.x;
  atomicAdd(&deg[ei[NEDGE + e]], 1);
}

__global__ __launch_bounds__(1024) void k_scan(const int* __restrict__ deg,
                                               int* __restrict__ rowptr, int* __restrict__ cursor){
  __shared__ int part[1024];
  int t = threadIdx.x;
  int base = t * 10;
  int loc[10];
  int s = 0;
  #pragma unroll
  for (int i = 0; i < 10; i++){
    int idx = base + i;
    int d = (idx < N_ATOM) ? deg[idx] : 0;
    loc[i] = s; s += d;
  }
  part[t] = s;
  __syncthreads();
  for (int off = 1; off < 1024; off <<= 1){
    int vp = 0;
    if (t >= off) vp = part[t - off];
    __syncthreads();
    part[t] += vp;
    __syncthreads();
  }
  int offset = (t == 0) ? 0 : part[t - 1];
  #pragma unroll
  for (int i = 0; i < 10; i++){
    int idx = base + i;
    if (idx < N_ATOM){ rowptr[idx] = offset + loc[i]; cursor[idx] = offset + loc[i]; }
  }
  if (t == 1023) rowptr[N_ATOM] = part[1023];
}

__global__ __launch_bounds__(256) void k_slot(const int* __restrict__ ei,
                                              int* __restrict__ cursor, int* __restrict__ slot){
  int e = blockIdx.x * 256 + threadIdx.x;
  int p = atomicAdd(&cursor[ei[NEDGE + e]], 1);
  slot[e] = p;
}

// ---------------------------------------------------------------- edge geometry -> dst-sorted slots
__global__ __launch_bounds__(256) void k_geo(const float* __restrict__ pos,
                                             const int* __restrict__ ei,
                                             const int* __restrict__ slot,
                                             int* __restrict__ srcs,
                                             float* __restrict__ rhs,
                                             float* __restrict__ rbfs,
                                             float* __restrict__ fcs){
  int e = blockIdx.x * 256 + threadIdx.x;
  int s = ei[e], d_ = ei[NEDGE + e];
  int p = slot[e];
  float rx = pos[d_*3+0] - pos[s*3+0];
  float ry = pos[d_*3+1] - pos[s*3+1];
  float rz = pos[d_*3+2] - pos[s*3+2];
  float d  = sqrtf(rx*rx + ry*ry + rz*rz + 1e-8f);
  float inv = 1.0f / d;
  srcs[p] = s;
  rhs[p*3+0] = rx*inv; rhs[p*3+1] = ry*inv; rhs[p*3+2] = rz*inv;
  float fcv = (d < 5.0f) ? 0.5f * (cosf(PI_F * d * 0.2f) + 1.0f) : 0.0f;
  fcs[p] = fcv;
  float base = PI_F * d * 0.2f;
  float sc = inv * fcv;
  #pragma unroll
  for (int k = 0; k < NB; k++){
    rbfs[(size_t)p*NB + k] = sinf(base * (float)(k+1)) * sc;
  }
}

// ---------------------------------------------------------------- MFMA node phi: LN + GEMM1 + silu + GEMM2
// 16 rows/block, 625 blocks. fp32 phi out.
__global__ __launch_bounds__(256) void k_node_phi(const float* __restrict__ x,
                                                  float* __restrict__ phi,
                                                  const float* __restrict__ ln_g, const float* __restrict__ ln_b,
                                                  const short* __restrict__ Wm1t, const float* __restrict__ bm1,
                                                  const short* __restrict__ Wm2t, const float* __restrict__ bm2){
  __shared__ short xn_s[16*136];
  __shared__ short h_s [16*136];
  __shared__ float mu_s[16], rs_s[16];
  int t = threadIdx.x;
  int row0 = blockIdx.x * 16;

  { // LN stats: 16 threads per row
    int r = t >> 4, q = t & 15;
    const float* xr = x + (size_t)(row0 + r) * F;
    float s = 0.f, ss = 0.f;
    #pragma unroll
    for (int i = 0; i < 8; i++){ float vv = xr[q + 16*i]; s += vv; ss += vv*vv; }
    #pragma unroll
    for (int m = 8; m >= 1; m >>= 1){ s += __shfl_xor(s, m, 64); ss += __shfl_xor(ss, m, 64); }
    if (q == 0){
      float mu = s * (1.0f/F);
      mu_s[r] = mu; rs_s[r] = rsqrtf(ss * (1.0f/F) - mu*mu + 1e-5f);
    }
  }
  __syncthreads();
  #pragma unroll
  for (int i = 0; i < 8; i++){              // xn fill (16*128 = 2048)
    int idx = t + 256*i; int r = idx >> 7, f = idx & 127;
    float vv = x[(size_t)(row0 + r)*F + f];
    xn_s[r*136 + f] = f2b((vv - mu_s[r]) * rs_s[r] * ln_g[f] + ln_b[f]);
  }
  __syncthreads();

  int l = t & 63, w = t >> 6;
  int kof = (l >> 4) * 8;
  int arow = l & 15;

  { // GEMM1: h = silu(xn @ Wm1 + bm1); 8 col-tiles, 2/wave
    bf16x8 af[4];
    #pragma unroll
    for (int ks = 0; ks < 4; ks++) af[ks] = *(const bf16x8*)&xn_s[arow*136 + ks*32 + kof];
    #pragma unroll
    for (int cc = 0; cc < 2; cc++){
      int col = (w*2 + cc)*16 + (l & 15);
      float bb = bm1[col];
      f32x4 acc = {bb, bb, bb, bb};
      #pragma unroll
      for (int ks = 0; ks < 4; ks++){
        bf16x8 bf = *(const bf16x8*)&Wm1t[col*F + ks*32 + kof];
        acc = MFMA16(af[ks], bf, acc);
      }
      #pragma unroll
      for (int i = 0; i < 4; i++) h_s[((l>>4)*4 + i)*136 + col] = f2b(silu_f(acc[i]));
    }
  }
  __syncthreads();
  { // GEMM2: phi = h @ Wm2 + bm2, fp32 out; 24 col-tiles, 6/wave
    bf16x8 ah[4];
    #pragma unroll
    for (int ks = 0; ks < 4; ks++) ah[ks] = *(const bf16x8*)&h_s[arow*136 + ks*32 + kof];
    #pragma unroll
    for (int cc = 0; cc < 6; cc++){
      int col = (w*6 + cc)*16 + (l & 15);
      float bb = bm2[col];
      f32x4 acc = {bb, bb, bb, bb};
      #pragma unroll
      for (int ks = 0; ks < 4; ks++){
        bf16x8 bf = *(const bf16x8*)&Wm2t[col*F + ks*32 + kof];
        acc = MFMA16(ah[ks], bf, acc);
      }
      #pragma unroll
      for (int i = 0; i < 4; i++)
        phi[(size_t)(row0 + (l>>4)*4 + i)*F3 + col] = acc[i];
    }
  }
}

// ---------------------------------------------------------------- OWNER-WAVE edge gather, 2-deep prefetch pipeline
// one wave per dst node; lane covers f and f+64; fp32 payloads (12 gathers/edge, 24 in flight).
__global__ __launch_bounds__(256) void k_edge_g(const int* __restrict__ rowptr,
                                                const int* __restrict__ srcs,
                                                const float* __restrict__ rbfs,
                                                const float* __restrict__ rhs,
                                                const float* __restrict__ fcs,
                                                const float* __restrict__ phi,
                                                const float* __restrict__ v,
                                                const float* __restrict__ Wrbf,
                                                const float* __restrict__ brbf,
                                                float* __restrict__ x,
                                                float* __restrict__ dv){
  __shared__ float W[NB * F3];                       // 30720 B
  int t = threadIdx.x;
  #pragma unroll
  for (int i = 0; i < (NB*F3)/256; i++) W[t + 256*i] = Wrbf[t + 256*i];
  __syncthreads();

  int wid = t >> 6, lane = t & 63;
  int n = blockIdx.x * 4 + wid;                      // 2500 blocks * 4 waves
  int f0 = lane, f1 = lane + 64;
  int r0 = rowptr[n], r1 = rowptr[n+1];

  float bs0  = brbf[f0],       bs1  = brbf[f1];
  float bvv0 = brbf[F + f0],   bvv1 = brbf[F + f1];
  float bvs0 = brbf[2*F + f0], bvs1 = brbf[2*F + f1];

  float ax0=0.f, ax1=0.f;
  float av00=0.f, av01=0.f, av10=0.f, av11=0.f, av20=0.f, av21=0.f;

  // prefetch registers (edge j+1 issued while edge j computes)
  float fcP, rh0P, rh1P, rh2P;
  float pA, pB, pC, pD, pE, pFv;
  float vA, vB, vC, vD, vE, vFv;
  #define PREF(JJ) do{ int s_ = srcs[JJ]; fcP = fcs[JJ]; \
      rh0P = rhs[(JJ)*3+0]; rh1P = rhs[(JJ)*3+1]; rh2P = rhs[(JJ)*3+2]; \
      const float* ps_ = phi + (size_t)s_ * F3; \
      const float* vs_ = v   + (size_t)s_ * 3 * F; \
      pA = ps_[f0];       pB = ps_[f1]; \
      pC = ps_[F + f0];   pD = ps_[F + f1]; \
      pE = ps_[2*F + f0]; pFv = ps_[2*F + f1]; \
      vA = vs_[f0];       vB = vs_[f1]; \
      vC = vs_[F + f0];   vD = vs_[F + f1]; \
      vE = vs_[2*F + f0]; vFv = vs_[2*F + f1]; }while(0)

  if (r0 < r1) PREF(r0);
  for (int j = r0; j < r1; ++j){
    // consume values prefetched one iteration ago
    float fcv = fcP, rh0 = rh0P, rh1 = rh1P, rh2 = rh2P;
    float pa = pA, pb = pB, pc = pC, pd = pD, pe = pE, pf = pFv;
    float va = vA, vb = vB, vc = vC, vd = vD, ve = vE, vf = vFv;
    if (j + 1 < r1) PREF(j + 1);                     // issue next-edge gathers now

    const float* rb = rbfs + (size_t)j * NB;
    float ws0=0.f, ws1=0.f, wv0=0.f, wv1=0.f, wq0=0.f, wq1=0.f;
    #pragma unroll
    for (int k = 0; k < NB; k++){
      float r = rb[k];                               // wave-uniform broadcast
      ws0 += r * W[k*F3 + f0];        ws1 += r * W[k*F3 + f1];
      wv0 += r * W[k*F3 + F + f0];    wv1 += r * W[k*F3 + F + f1];
      wq0 += r * W[k*F3 + 2*F + f0];  wq1 += r * W[k*F3 + 2*F + f1];
    }
    float ms0  = pa * (ws0 + bs0 *fcv);
    float ms1  = pb * (ws1 + bs1 *fcv);
    float mvv0 = pc * (wv0 + bvv0*fcv);
    float mvv1 = pd * (wv1 + bvv1*fcv);
    float mvs0 = pe * (wq0 + bvs0*fcv);
    float mvs1 = pf * (wq1 + bvs1*fcv);
    ax0 += ms0; ax1 += ms1;
    av00 += mvv0*va + mvs0*rh0;  av01 += mvv1*vb + mvs1*rh0;
    av10 += mvv0*vc + mvs0*rh1;  av11 += mvv1*vd + mvs1*rh1;
    av20 += mvv0*ve + mvs0*rh2;  av21 += mvv1*vf + mvs1*rh2;
  }
  #undef PREF

  size_t xb = (size_t)n * F;
  x[xb + f0] += ax0;  x[xb + f1] += ax1;
  size_t vb0 = (size_t)n * 3 * F;
  dv[vb0 + f0]       = av00;  dv[vb0 + f1]       = av01;
  dv[vb0 + F + f0]   = av10;  dv[vb0 + F + f1]   = av11;
  dv[vb0 + 2*F + f0] = av20;  dv[vb0 + 2*F + f1] = av21;
}

// ---------------------------------------------------------------- MFMA node update: Uv/Vv, LN2, gated MLP, x/v update
// 16 nodes (48 v-rows)/block, 625 blocks. vnew = v + dv formed in fp32 here.
__global__ __launch_bounds__(256) void k_node_upd(float* __restrict__ x, float* __restrict__ v,
                                                  const float* __restrict__ dv,
                                                  const short* __restrict__ Uwt, const short* __restrict__ Vwt,
                                                  const float* __restrict__ ln2_g, const float* __restrict__ ln2_b,
                                                  const short* __restrict__ Wu1t, const float* __restrict__ bu1,
                                                  const short* __restrict__ Wu2t, const float* __restrict__ bu2){
  __shared__ __align__(16) char smem[59776];
  short* vt   = (short*)smem;                          // [48][136] bf16 (v+dv)
  short* Uv_s = (short*)(smem + 13056);                // [48][136]
  char*  R    = smem + 26112;                          // union region (24576 B)
  short* Vv_s = (short*)R;                             // [48][136] (phases 1-2)
  short* ab   = (short*)(R + 13056);                   // [16][264] concat A (phases 2-3)
  float* a_s  = (float*)R;                             // [16][384] (phases 4-5)
  short* h2   = (short*)(smem + 50688);                // [16][136]
  short* duv  = (short*)(smem + 55040);                // [16][136]
  float* mu_s = (float*)(smem + 59392);                // [16]
  float* rs_s = mu_s + 16;

  int t = threadIdx.x;
  int n0 = blockIdx.x * 16;

  { // LN2 stats on x: 16 threads/row
    int r = t >> 4, q = t & 15;
    const float* xr = x + (size_t)(n0 + r) * F;
    float s = 0.f, ss = 0.f;
    #pragma unroll
    for (int i = 0; i < 8; i++){ float vv = xr[q + 16*i]; s += vv; ss += vv*vv; }
    #pragma unroll
    for (int m = 8; m >= 1; m >>= 1){ s += __shfl_xor(s, m, 64); ss += __shfl_xor(ss, m, 64); }
    if (q == 0){ float mu = s*(1.0f/F); mu_s[r] = mu; rs_s[r] = rsqrtf(ss*(1.0f/F) - mu*mu + 1e-5f); }
  }
  #pragma unroll
  for (int i = 0; i < 24; i++){               // (v+dv) -> bf16 LDS (48*128 = 6144)
    int idx = t + 256*i;
    size_t g = (size_t)n0*3*F + idx;
    vt[(idx >> 7)*136 + (idx & 127)] = f2b(v[g] + dv[g]);
  }
  __syncthreads();

  int l = t & 63, w = t >> 6;
  int kof = (l >> 4) * 8;

  { // Uv/Vv GEMMs: 12 jobs (3 rowtiles x {U,V} x 2 col-halves), 3 per wave
    #pragma unroll
    for (int jj = 0; jj < 3; jj++){
      int job = w*3 + jj;
      int rt = job >> 2, rem = job & 3, mat = rem >> 1, ch = rem & 1;
      const short* Bt = mat ? Vwt : Uwt;
      short* Out = mat ? Vv_s : Uv_s;
      bf16x8 af[4];
      #pragma unroll
      for (int ks = 0; ks < 4; ks++) af[ks] = *(const bf16x8*)&vt[(rt*16 + (l&15))*136 + ks*32 + kof];
      #pragma unroll
      for (int ct = 0; ct < 4; ct++){
        int col = ch*64 + ct*16 + (l & 15);
        f32x4 acc = {0.f, 0.f, 0.f, 0.f};
        #pragma unroll
        for (int ks = 0; ks < 4; ks++){
          bf16x8 bf = *(const bf16x8*)&Bt[col*F + ks*32 + kof];
          acc = MFMA16(af[ks], bf, acc);
        }
        #pragma unroll
        for (int i = 0; i < 4; i++) Out[(rt*16 + (l>>4)*4 + i)*136 + col] = f2b(acc[i]);
      }
    }
  }
  __syncthreads();

  { // xn2, vnorm, duv
    #pragma unroll
    for (int i = 0; i < 8; i++){
      int idx = t + 256*i; int n = idx >> 7, f = idx & 127;
      float xv = x[(size_t)(n0 + n)*F + f];
      ab[n*264 + f] = f2b((xv - mu_s[n]) * rs_s[n] * ln2_g[f] + ln2_b[f]);
      float v0 = b2f(Vv_s[(3*n+0)*136 + f]), v1 = b2f(Vv_s[(3*n+1)*136 + f]), v2 = b2f(Vv_s[(3*n+2)*136 + f]);
      float u0 = b2f(Uv_s[(3*n+0)*136 + f]), u1 = b2f(Uv_s[(3*n+1)*136 + f]), u2 = b2f(Uv_s[(3*n+2)*136 + f]);
      ab[n*264 + 128 + f] = f2b(sqrtf(v0*v0 + v1*v1 + v2*v2 + 1e-8f));
      duv[n*136 + f] = f2b(u0*v0 + u1*v1 + u2*v2);
    }
  }
  __syncthreads();

  { // Wu1 GEMM (K=256) + silu -> h2; 8 col-tiles, 2/wave
    bf16x8 af[8];
    #pragma unroll
    for (int ks = 0; ks < 8; ks++) af[ks] = *(const bf16x8*)&ab[(l&15)*264 + ks*32 + kof];
    #pragma unroll
    for (int cc = 0; cc < 2; cc++){
      int col = (w*2 + cc)*16 + (l & 15);
      float bb = bu1[col];
      f32x4 acc = {bb, bb, bb, bb};
      #pragma unroll
      for (int ks = 0; ks < 8; ks++){
        bf16x8 bf = *(const bf16x8*)&Wu1t[col*256 + ks*32 + kof];
        acc = MFMA16(af[ks], bf, acc);
      }
      #pragma unroll
      for (int i = 0; i < 4; i++) h2[((l>>4)*4 + i)*136 + col] = f2b(silu_f(acc[i]));
    }
  }
  __syncthreads();

  { // Wu2 GEMM -> a_s fp32; 24 col-tiles, 6/wave
    bf16x8 af[4];
    #pragma unroll
    for (int ks = 0; ks < 4; ks++) af[ks] = *(const bf16x8*)&h2[(l&15)*136 + ks*32 + kof];
    #pragma unroll
    for (int cc = 0; cc < 6; cc++){
      int col = (w*6 + cc)*16 + (l & 15);
      float bb = bu2[col];
      f32x4 acc = {bb, bb, bb, bb};
      #pragma unroll
      for (int ks = 0; ks < 4; ks++){
        bf16x8 bf = *(const bf16x8*)&Wu2t[col*F + ks*32 + kof];
        acc = MFMA16(af[ks], bf, acc);
      }
      #pragma unroll
      for (int i = 0; i < 4; i++) a_s[((l>>4)*4 + i)*384 + col] = acc[i];
    }
  }
  __syncthreads();

  { // final updates: fp32 state
    #pragma unroll
    for (int i = 0; i < 8; i++){
      int idx = t + 256*i; int n = idx >> 7, f = idx & 127;
      float avv = a_s[n*384 + f], asv = a_s[n*384 + 128 + f], ass = a_s[n*384 + 256 + f];
      size_t xr_ = (size_t)(n0 + n)*F + f;
      x[xr_] = x[xr_] + asv * b2f(duv[n*136 + f]) + ass;
      #pragma unroll
      for (int c = 0; c < 3; c++){
        size_t vr = (size_t)((n0 + n)*3 + c)*F + f;
        v[vr] = v[vr] + dv[vr] + avv * b2f(Uv_s[(3*n + c)*136 + f]);
      }
    }
  }
}

// ---------------------------------------------------------------- output head + global sum
__global__ __launch_bounds__(256) void k_out(const float* __restrict__ x,
                                             const float* __restrict__ Wo1, const float* __restrict__ bo1,
                                             const float* __restrict__ Wo2, const float* __restrict__ bo2,
                                             float* __restrict__ out){
  __shared__ float xl[8][F];
  __shared__ float hl[8][F];
  __shared__ float er[8];
  int t = threadIdx.x; int n0 = blockIdx.x * 8;
  #pragma unroll
  for (int i = 0; i < 4; i++){ int idx = t + 256*i; ((float*)xl)[idx] = x[(size_t)n0*F + idx]; }
  __syncthreads();
  { int g = t & 127, grp = t >> 7;
    float acc[4];
    #pragma unroll
    for (int n = 0; n < 4; n++) acc[n] = bo1[g];
    for (int k = 0; k < F; k++){
      float w = Wo1[k*F + g];
      #pragma unroll
      for (int n = 0; n < 4; n++) acc[n] += xl[grp*4+n][k] * w;
    }
    #pragma unroll
    for (int n = 0; n < 4; n++) hl[grp*4+n][g] = silu_f(acc[n]);
  }
  __syncthreads();
  { int r = t >> 5, lq = t & 31;
    float s = 0.f;
    #pragma unroll
    for (int i = 0; i < 4; i++) s += hl[r][lq + 32*i] * Wo2[lq + 32*i];
    #pragma unroll
    for (int m = 16; m >= 1; m >>= 1) s += __shfl_xor(s, m, 64);
    if (lq == 0) er[r] = s + bo2[0];
  }
  __syncthreads();
  if (t == 0){
    float s = 0.f;
    #pragma unroll
    for (int r = 0; r < 8; r++) s += er[r];
    unsafeAtomicAdd(out, s);
  }
}

// ----------------------------------------------------------------
extern "C" void kernel_launch(void* const* d_in, const int* in_sizes, int n_in,
                              void* d_out, int out_size, void* d_ws, size_t ws_size,
                              hipStream_t stream){
  const float* pos     = (const float*)d_in[0];
  const int*   z       = (const int*)  d_in[1];
  const int*   ei      = (const int*)  d_in[2];
  const float* z_embed = (const float*)d_in[3];
  const float* Wrbf    = (const float*)d_in[4];
  const float* brbf    = (const float*)d_in[5];
  const float* ln_g    = (const float*)d_in[6];
  const float* ln_b    = (const float*)d_in[7];
  const float* Wm1     = (const float*)d_in[8];
  const float* bm1     = (const float*)d_in[9];
  const float* Wm2     = (const float*)d_in[10];
  const float* bm2     = (const float*)d_in[11];
  const float* Uw      = (const float*)d_in[12];
  const float* Vw      = (const float*)d_in[13];
  const float* ln2_g   = (const float*)d_in[14];
  const float* ln2_b   = (const float*)d_in[15];
  const float* Wu1     = (const float*)d_in[16];
  const float* bu1     = (const float*)d_in[17];
  const float* Wu2     = (const float*)d_in[18];
  const float* bu2     = (const float*)d_in[19];
  const float* Wo1     = (const float*)d_in[20];
  const float* bo1     = (const float*)d_in[21];
  const float* Wo2     = (const float*)d_in[22];
  const float* bo2     = (const float*)d_in[23];

  float* ws = (float*)d_ws;
  size_t o = 0;
  float* x     = ws + o; o += (size_t)N_ATOM * F;
  float* v     = ws + o; o += (size_t)N_ATOM * 3 * F;
  float* dv    = ws + o; o += (size_t)N_ATOM * 3 * F;
  float* phi   = ws + o; o += (size_t)N_ATOM * 3 * F;
  float* rhs   = ws + o; o += (size_t)NEDGE * 3;
  float* rbfs  = ws + o; o += (size_t)NEDGE * NB;
  float* fcs   = ws + o; o += (size_t)NEDGE;
  int*   rowptr= (int*)(ws + o); o += N_ATOM + 16;
  int*   srcs  = (int*)(ws + o); o += NEDGE;
  short* wt    = (short*)(ws + o); o += 270336 + 8;   // 540672 bf16 weights
  // transient CSR-build arrays alias the dv region (dv first written in
  // k_edge_g, strictly after k_slot/k_geo complete)
  int* deg    = (int*)dv;
  int* cursor = deg + 10240;
  int* slot   = cursor + 10240;

  short* wm1t = wt;
  short* wm2t = wt + 49152;
  short* uwt  = wt + 196608;
  short* vwt  = wt + 245760;
  short* wu1t = wt + 294912;
  short* wu2t = wt + 393216;

  hipMemsetAsync(d_out, 0, sizeof(float), stream);
  hipMemsetAsync(deg, 0, N_ATOM * sizeof(int), stream);
  k_prep<<<2112, 256, 0, stream>>>(Wm1, Wm2, Uw, Vw, Wu1, Wu2, wt);
  k_hist<<<NEDGE/256, 256, 0, stream>>>(ei, deg);
  k_scan<<<1, 1024, 0, stream>>>(deg, rowptr, cursor);
  k_slot<<<NEDGE/256, 256, 0, stream>>>(ei, cursor, slot);
  k_geo <<<NEDGE/256, 256, 0, stream>>>(pos, ei, slot, srcs, rhs, rbfs, fcs);
  k_init<<<(N_ATOM*3*F + 255)/256, 256, 0, stream>>>(z_embed, z, x, v);

  for (int b = 0; b < NBLK; b++){
    k_node_phi<<<N_ATOM/16, 256, 0, stream>>>(x, phi,
        ln_g + b*F, ln_b + b*F, wm1t + b*16384, bm1 + b*F,
        wm2t + b*49152, bm2 + b*F3);
    k_edge_g<<<N_ATOM/4, 256, 0, stream>>>(rowptr, srcs, rbfs, rhs, fcs,
        phi, v, Wrbf + (size_t)b*NB*F3, brbf + b*F3, x, dv);
    k_node_upd<<<N_ATOM/16, 256, 0, stream>>>(x, v, dv,
        uwt + b*16384, vwt + b*16384,
        ln2_g + b*F, ln2_b + b*F,
        wu1t + b*32768, bu1 + b*F,
        wu2t + b*49152, bu2 + b*F3);
  }
  k_out<<<N_ATOM/8, 256, 0, stream>>>(x, Wo1, bo1, Wo2, bo2, (float*)d_out);
}

// Round 16
// 639.318 us; speedup vs baseline: 1.2761x; 1.1147x over previous
//
#include <hip/hip_runtime.h>
#include <math.h>

#define N_ATOM 10000
#define NEDGE  160000
#define F      128
#define F3     384
#define NB     20
#define NBLK   3
#define PI_F   3.14159265358979323846f

typedef __attribute__((ext_vector_type(8))) short bf16x8;
typedef __attribute__((ext_vector_type(4))) float f32x4;
#define MFMA16(a,b,c) __builtin_amdgcn_mfma_f32_16x16x32_bf16(a,b,c,0,0,0)

__device__ __forceinline__ float silu_f(float x){ return x / (1.0f + __expf(-x)); }
__device__ __forceinline__ short f2b(float f){            // fp32 -> bf16 RNE
  unsigned u = __float_as_uint(f);
  u += 0x7fff + ((u >> 16) & 1);
  return (short)(u >> 16);
}
__device__ __forceinline__ float b2f(short s){
  return __uint_as_float(((unsigned)(unsigned short)s) << 16);
}

// ---------------------------------------------------------------- weight cast+transpose -> bf16 [N][K]
__global__ __launch_bounds__(256) void k_prep(const float* __restrict__ Wm1, const float* __restrict__ Wm2,
                                              const float* __restrict__ Uw,  const float* __restrict__ Vw,
                                              const float* __restrict__ Wu1, const float* __restrict__ Wu2,
                                              short* __restrict__ wt){
  int idx = blockIdx.x * 256 + threadIdx.x;          // 540672 total
  short* wm1t = wt;                                   // 3*[128][128]
  short* wm2t = wt + 49152;                           // 3*[384][128]
  short* uwt  = wt + 196608;                          // 3*[128][128]
  short* vwt  = wt + 245760;                          // 3*[128][128]
  short* wu1t = wt + 294912;                          // 3*[128][256]
  short* wu2t = wt + 393216;                          // 3*[384][128]
  if (idx < 49152){
    int b = idx >> 14, r = idx & 16383, n = r >> 7, k = r & 127;
    wm1t[idx] = f2b(Wm1[b*16384 + k*128 + n]);
  } else if (idx < 196608){
    int j = idx - 49152;
    int b = j / 49152, r = j % 49152, n = r >> 7, k = r & 127;
    wm2t[j] = f2b(Wm2[b*49152 + k*384 + n]);
  } else if (idx < 245760){
    int j = idx - 196608;
    int b = j >> 14, r = j & 16383, n = r >> 7, k = r & 127;
    uwt[j] = f2b(Uw[b*16384 + k*128 + n]);
  } else if (idx < 294912){
    int j = idx - 245760;
    int b = j >> 14, r = j & 16383, n = r >> 7, k = r & 127;
    vwt[j] = f2b(Vw[b*16384 + k*128 + n]);
  } else if (idx < 393216){
    int j = idx - 294912;
    int b = j >> 15, r = j & 32767, n = r >> 8, k = r & 255;
    wu1t[j] = f2b(Wu1[b*32768 + k*128 + n]);
  } else if (idx < 540672){
    int j = idx - 393216;
    int b = j / 49152, r = j % 49152, n = r >> 7, k = r & 127;
    wu2t[j] = f2b(Wu2[b*49152 + k*384 + n]);
  }
}

// ---------------------------------------------------------------- init: x = z_embed[z], v = 0
__global__ __launch_bounds__(256) void k_init(const float* __restrict__ z_embed,
                                              const int* __restrict__ z,
                                              float* __restrict__ x, float* __restrict__ v){
  int idx = blockIdx.x * 256 + threadIdx.x;
  if (idx < N_ATOM * F){
    int i = idx >> 7, f = idx & 127;
    x[idx] = z_embed[z[i] * F + f];
  }
  if (idx < N_ATOM * 3 * F) v[idx] = 0.0f;
}

// ---------------------------------------------------------------- CSR build
__global__ __launch_bounds__(256) void k_hist(const int* __restrict__ ei, int* __restrict__ deg){
  int e = blockIdx.x * 256 + threadIdx.x;
  atomicAdd(&deg[ei[NEDGE + e]], 1);
}

__global__ __launch_bounds__(1024) void k_scan(const int* __restrict__ deg,
                                               int* __restrict__ rowptr, int* __restrict__ cursor){
  __shared__ int part[1024];
  int t = threadIdx.x;
  int base = t * 10;
  int loc[10];
  int s = 0;
  #pragma unroll
  for (int i = 0; i < 10; i++){
    int idx = base + i;
    int d = (idx < N_ATOM) ? deg[idx] : 0;
    loc[i] = s; s += d;
  }
  part[t] = s;
  __syncthreads();
  for (int off = 1; off < 1024; off <<= 1){
    int vp = 0;
    if (t >= off) vp = part[t - off];
    __syncthreads();
    part[t] += vp;
    __syncthreads();
  }
  int offset = (t == 0) ? 0 : part[t - 1];
  #pragma unroll
  for (int i = 0; i < 10; i++){
    int idx = base + i;
    if (idx < N_ATOM){ rowptr[idx] = offset + loc[i]; cursor[idx] = offset + loc[i]; }
  }
  if (t == 1023) rowptr[N_ATOM] = part[1023];
}

__global__ __launch_bounds__(256) void k_slot(const int* __restrict__ ei,
                                              int* __restrict__ cursor, int* __restrict__ slot){
  int e = blockIdx.x * 256 + threadIdx.x;
  int p = atomicAdd(&cursor[ei[NEDGE + e]], 1);
  slot[e] = p;
}

// ---------------------------------------------------------------- edge geometry -> dst-sorted slots
__global__ __launch_bounds__(256) void k_geo(const float* __restrict__ pos,
                                             const int* __restrict__ ei,
                                             const int* __restrict__ slot,
                                             int* __restrict__ srcs,
                                             float* __restrict__ rhs,
                                             float* __restrict__ rbfs,
                                             float* __restrict__ fcs){
  int e = blockIdx.x * 256 + threadIdx.x;
  int s = ei[e], d_ = ei[NEDGE + e];
  int p = slot[e];
  float rx = pos[d_*3+0] - pos[s*3+0];
  float ry = pos[d_*3+1] - pos[s*3+1];
  float rz = pos[d_*3+2] - pos[s*3+2];
  float d  = sqrtf(rx*rx + ry*ry + rz*rz + 1e-8f);
  float inv = 1.0f / d;
  srcs[p] = s;
  rhs[p*3+0] = rx*inv; rhs[p*3+1] = ry*inv; rhs[p*3+2] = rz*inv;
  float fcv = (d < 5.0f) ? 0.5f * (cosf(PI_F * d * 0.2f) + 1.0f) : 0.0f;
  fcs[p] = fcv;
  float base = PI_F * d * 0.2f;
  float sc = inv * fcv;
  #pragma unroll
  for (int k = 0; k < NB; k++){
    rbfs[(size_t)p*NB + k] = sinf(base * (float)(k+1)) * sc;
  }
}

// ---------------------------------------------------------------- MFMA node phi: LN + GEMM1 + silu + GEMM2
// 16 rows/block, 625 blocks. fp32 phi out.
__global__ __launch_bounds__(256) void k_node_phi(const float* __restrict__ x,
                                                  float* __restrict__ phi,
                                                  const float* __restrict__ ln_g, const float* __restrict__ ln_b,
                                                  const short* __restrict__ Wm1t, const float* __restrict__ bm1,
                                                  const short* __restrict__ Wm2t, const float* __restrict__ bm2){
  __shared__ short xn_s[16*136];
  __shared__ short h_s [16*136];
  __shared__ float mu_s[16], rs_s[16];
  int t = threadIdx.x;
  int row0 = blockIdx.x * 16;

  { // LN stats: 16 threads per row
    int r = t >> 4, q = t & 15;
    const float* xr = x + (size_t)(row0 + r) * F;
    float s = 0.f, ss = 0.f;
    #pragma unroll
    for (int i = 0; i < 8; i++){ float vv = xr[q + 16*i]; s += vv; ss += vv*vv; }
    #pragma unroll
    for (int m = 8; m >= 1; m >>= 1){ s += __shfl_xor(s, m, 64); ss += __shfl_xor(ss, m, 64); }
    if (q == 0){
      float mu = s * (1.0f/F);
      mu_s[r] = mu; rs_s[r] = rsqrtf(ss * (1.0f/F) - mu*mu + 1e-5f);
    }
  }
  __syncthreads();
  #pragma unroll
  for (int i = 0; i < 8; i++){              // xn fill (16*128 = 2048)
    int idx = t + 256*i; int r = idx >> 7, f = idx & 127;
    float vv = x[(size_t)(row0 + r)*F + f];
    xn_s[r*136 + f] = f2b((vv - mu_s[r]) * rs_s[r] * ln_g[f] + ln_b[f]);
  }
  __syncthreads();

  int l = t & 63, w = t >> 6;
  int kof = (l >> 4) * 8;
  int arow = l & 15;

  { // GEMM1: h = silu(xn @ Wm1 + bm1); 8 col-tiles, 2/wave
    bf16x8 af[4];
    #pragma unroll
    for (int ks = 0; ks < 4; ks++) af[ks] = *(const bf16x8*)&xn_s[arow*136 + ks*32 + kof];
    #pragma unroll
    for (int cc = 0; cc < 2; cc++){
      int col = (w*2 + cc)*16 + (l & 15);
      float bb = bm1[col];
      f32x4 acc = {bb, bb, bb, bb};
      #pragma unroll
      for (int ks = 0; ks < 4; ks++){
        bf16x8 bf = *(const bf16x8*)&Wm1t[col*F + ks*32 + kof];
        acc = MFMA16(af[ks], bf, acc);
      }
      #pragma unroll
      for (int i = 0; i < 4; i++) h_s[((l>>4)*4 + i)*136 + col] = f2b(silu_f(acc[i]));
    }
  }
  __syncthreads();
  { // GEMM2: phi = h @ Wm2 + bm2, fp32 out; 24 col-tiles, 6/wave
    bf16x8 ah[4];
    #pragma unroll
    for (int ks = 0; ks < 4; ks++) ah[ks] = *(const bf16x8*)&h_s[arow*136 + ks*32 + kof];
    #pragma unroll
    for (int cc = 0; cc < 6; cc++){
      int col = (w*6 + cc)*16 + (l & 15);
      float bb = bm2[col];
      f32x4 acc = {bb, bb, bb, bb};
      #pragma unroll
      for (int ks = 0; ks < 4; ks++){
        bf16x8 bf = *(const bf16x8*)&Wm2t[col*F + ks*32 + kof];
        acc = MFMA16(ah[ks], bf, acc);
      }
      #pragma unroll
      for (int i = 0; i < 4; i++)
        phi[(size_t)(row0 + (l>>4)*4 + i)*F3 + col] = acc[i];
    }
  }
}

// ---------------------------------------------------------------- OWNER-WAVE edge gather (compiler-scheduled loads)
// one wave per dst node; lane covers f and f+64; fp32 payloads; zero atomics.
__global__ __launch_bounds__(256) void k_edge_g(const int* __restrict__ rowptr,
                                                const int* __restrict__ srcs,
                                                const float* __restrict__ rbfs,
                                                const float* __restrict__ rhs,
                                                const float* __restrict__ fcs,
                                                const float* __restrict__ phi,
                                                const float* __restrict__ v,
                                                const float* __restrict__ Wrbf,
                                                const float* __restrict__ brbf,
                                                float* __restrict__ x,
                                                float* __restrict__ dv){
  __shared__ float W[NB * F3];                       // 30720 B
  int t = threadIdx.x;
  #pragma unroll
  for (int i = 0; i < (NB*F3)/256; i++) W[t + 256*i] = Wrbf[t + 256*i];
  __syncthreads();

  int wid = t >> 6, lane = t & 63;
  int n = blockIdx.x * 4 + wid;                      // 2500 blocks * 4 waves
  int f0 = lane, f1 = lane + 64;
  int r0 = rowptr[n], r1 = rowptr[n+1];

  float bs0  = brbf[f0],       bs1  = brbf[f1];
  float bvv0 = brbf[F + f0],   bvv1 = brbf[F + f1];
  float bvs0 = brbf[2*F + f0], bvs1 = brbf[2*F + f1];

  float ax0=0.f, ax1=0.f;
  float av00=0.f, av01=0.f, av10=0.f, av11=0.f, av20=0.f, av21=0.f;

  for (int j = r0; j < r1; ++j){
    int s = srcs[j];
    float fcv = fcs[j];
    float rh0 = rhs[j*3+0], rh1 = rhs[j*3+1], rh2 = rhs[j*3+2];
    const float* rb = rbfs + (size_t)j * NB;
    float ws0=0.f, ws1=0.f, wv0=0.f, wv1=0.f, wq0=0.f, wq1=0.f;
    #pragma unroll
    for (int k = 0; k < NB; k++){
      float r = rb[k];                               // wave-uniform broadcast
      ws0 += r * W[k*F3 + f0];        ws1 += r * W[k*F3 + f1];
      wv0 += r * W[k*F3 + F + f0];    wv1 += r * W[k*F3 + F + f1];
      wq0 += r * W[k*F3 + 2*F + f0];  wq1 += r * W[k*F3 + 2*F + f1];
    }
    const float* ps = phi + (size_t)s * F3;
    const float* vs = v   + (size_t)s * 3 * F;
    float ms0  = ps[f0]       * (ws0 + bs0 *fcv);
    float ms1  = ps[f1]       * (ws1 + bs1 *fcv);
    float mvv0 = ps[F + f0]   * (wv0 + bvv0*fcv);
    float mvv1 = ps[F + f1]   * (wv1 + bvv1*fcv);
    float mvs0 = ps[2*F + f0] * (wq0 + bvs0*fcv);
    float mvs1 = ps[2*F + f1] * (wq1 + bvs1*fcv);
    ax0 += ms0; ax1 += ms1;
    av00 += mvv0*vs[f0]       + mvs0*rh0;  av01 += mvv1*vs[f1]       + mvs1*rh0;
    av10 += mvv0*vs[F + f0]   + mvs0*rh1;  av11 += mvv1*vs[F + f1]   + mvs1*rh1;
    av20 += mvv0*vs[2*F + f0] + mvs0*rh2;  av21 += mvv1*vs[2*F + f1] + mvs1*rh2;
  }

  size_t xb = (size_t)n * F;
  x[xb + f0] += ax0;  x[xb + f1] += ax1;
  size_t vb0 = (size_t)n * 3 * F;
  dv[vb0 + f0]       = av00;  dv[vb0 + f1]       = av01;
  dv[vb0 + F + f0]   = av10;  dv[vb0 + F + f1]   = av11;
  dv[vb0 + 2*F + f0] = av20;  dv[vb0 + 2*F + f1] = av21;
}

// ---------------------------------------------------------------- MFMA node update: Uv/Vv, LN2, gated MLP, x/v update
// 16 nodes (48 v-rows)/block, 625 blocks. vnew = v + dv formed in fp32 here.
__global__ __launch_bounds__(256) void k_node_upd(float* __restrict__ x, float* __restrict__ v,
                                                  const float* __restrict__ dv,
                                                  const short* __restrict__ Uwt, const short* __restrict__ Vwt,
                                                  const float* __restrict__ ln2_g, const float* __restrict__ ln2_b,
                                                  const short* __restrict__ Wu1t, const float* __restrict__ bu1,
                                                  const short* __restrict__ Wu2t, const float* __restrict__ bu2){
  __shared__ __align__(16) char smem[59776];
  short* vt   = (short*)smem;                          // [48][136] bf16 (v+dv)
  short* Uv_s = (short*)(smem + 13056);                // [48][136]
  char*  R    = smem + 26112;                          // union region (24576 B)
  short* Vv_s = (short*)R;                             // [48][136] (phases 1-2)
  short* ab   = (short*)(R + 13056);                   // [16][264] concat A (phases 2-3)
  float* a_s  = (float*)R;                             // [16][384] (phases 4-5)
  short* h2   = (short*)(smem + 50688);                // [16][136]
  short* duv  = (short*)(smem + 55040);                // [16][136]
  float* mu_s = (float*)(smem + 59392);                // [16]
  float* rs_s = mu_s + 16;

  int t = threadIdx.x;
  int n0 = blockIdx.x * 16;

  { // LN2 stats on x: 16 threads/row
    int r = t >> 4, q = t & 15;
    const float* xr = x + (size_t)(n0 + r) * F;
    float s = 0.f, ss = 0.f;
    #pragma unroll
    for (int i = 0; i < 8; i++){ float vv = xr[q + 16*i]; s += vv; ss += vv*vv; }
    #pragma unroll
    for (int m = 8; m >= 1; m >>= 1){ s += __shfl_xor(s, m, 64); ss += __shfl_xor(ss, m, 64); }
    if (q == 0){ float mu = s*(1.0f/F); mu_s[r] = mu; rs_s[r] = rsqrtf(ss*(1.0f/F) - mu*mu + 1e-5f); }
  }
  #pragma unroll
  for (int i = 0; i < 24; i++){               // (v+dv) -> bf16 LDS (48*128 = 6144)
    int idx = t + 256*i;
    size_t g = (size_t)n0*3*F + idx;
    vt[(idx >> 7)*136 + (idx & 127)] = f2b(v[g] + dv[g]);
  }
  __syncthreads();

  int l = t & 63, w = t >> 6;
  int kof = (l >> 4) * 8;

  { // Uv/Vv GEMMs: 12 jobs (3 rowtiles x {U,V} x 2 col-halves), 3 per wave
    #pragma unroll
    for (int jj = 0; jj < 3; jj++){
      int job = w*3 + jj;
      int rt = job >> 2, rem = job & 3, mat = rem >> 1, ch = rem & 1;
      const short* Bt = mat ? Vwt : Uwt;
      short* Out = mat ? Vv_s : Uv_s;
      bf16x8 af[4];
      #pragma unroll
      for (int ks = 0; ks < 4; ks++) af[ks] = *(const bf16x8*)&vt[(rt*16 + (l&15))*136 + ks*32 + kof];
      #pragma unroll
      for (int ct = 0; ct < 4; ct++){
        int col = ch*64 + ct*16 + (l & 15);
        f32x4 acc = {0.f, 0.f, 0.f, 0.f};
        #pragma unroll
        for (int ks = 0; ks < 4; ks++){
          bf16x8 bf = *(const bf16x8*)&Bt[col*F + ks*32 + kof];
          acc = MFMA16(af[ks], bf, acc);
        }
        #pragma unroll
        for (int i = 0; i < 4; i++) Out[(rt*16 + (l>>4)*4 + i)*136 + col] = f2b(acc[i]);
      }
    }
  }
  __syncthreads();

  { // xn2, vnorm, duv
    #pragma unroll
    for (int i = 0; i < 8; i++){
      int idx = t + 256*i; int n = idx >> 7, f = idx & 127;
      float xv = x[(size_t)(n0 + n)*F + f];
      ab[n*264 + f] = f2b((xv - mu_s[n]) * rs_s[n] * ln2_g[f] + ln2_b[f]);
      float v0 = b2f(Vv_s[(3*n+0)*136 + f]), v1 = b2f(Vv_s[(3*n+1)*136 + f]), v2 = b2f(Vv_s[(3*n+2)*136 + f]);
      float u0 = b2f(Uv_s[(3*n+0)*136 + f]), u1 = b2f(Uv_s[(3*n+1)*136 + f]), u2 = b2f(Uv_s[(3*n+2)*136 + f]);
      ab[n*264 + 128 + f] = f2b(sqrtf(v0*v0 + v1*v1 + v2*v2 + 1e-8f));
      duv[n*136 + f] = f2b(u0*v0 + u1*v1 + u2*v2);
    }
  }
  __syncthreads();

  { // Wu1 GEMM (K=256) + silu -> h2; 8 col-tiles, 2/wave
    bf16x8 af[8];
    #pragma unroll
    for (int ks = 0; ks < 8; ks++) af[ks] = *(const bf16x8*)&ab[(l&15)*264 + ks*32 + kof];
    #pragma unroll
    for (int cc = 0; cc < 2; cc++){
      int col = (w*2 + cc)*16 + (l & 15);
      float bb = bu1[col];
      f32x4 acc = {bb, bb, bb, bb};
      #pragma unroll
      for (int ks = 0; ks < 8; ks++){
        bf16x8 bf = *(const bf16x8*)&Wu1t[col*256 + ks*32 + kof];
        acc = MFMA16(af[ks], bf, acc);
      }
      #pragma unroll
      for (int i = 0; i < 4; i++) h2[((l>>4)*4 + i)*136 + col] = f2b(silu_f(acc[i]));
    }
  }
  __syncthreads();

  { // Wu2 GEMM -> a_s fp32; 24 col-tiles, 6/wave
    bf16x8 af[4];
    #pragma unroll
    for (int ks = 0; ks < 4; ks++) af[ks] = *(const bf16x8*)&h2[(l&15)*136 + ks*32 + kof];
    #pragma unroll
    for (int cc = 0; cc < 6; cc++){
      int col = (w*6 + cc)*16 + (l & 15);
      float bb = bu2[col];
      f32x4 acc = {bb, bb, bb, bb};
      #pragma unroll
      for (int ks = 0; ks < 4; ks++){
        bf16x8 bf = *(const bf16x8*)&Wu2t[col*F + ks*32 + kof];
        acc = MFMA16(af[ks], bf, acc);
      }
      #pragma unroll
      for (int i = 0; i < 4; i++) a_s[((l>>4)*4 + i)*384 + col] = acc[i];
    }
  }
  __syncthreads();

  { // final updates: fp32 state
    #pragma unroll
    for (int i = 0; i < 8; i++){
      int idx = t + 256*i; int n = idx >> 7, f = idx & 127;
      float avv = a_s[n*384 + f], asv = a_s[n*384 + 128 + f], ass = a_s[n*384 + 256 + f];
      size_t xr_ = (size_t)(n0 + n)*F + f;
      x[xr_] = x[xr_] + asv * b2f(duv[n*136 + f]) + ass;
      #pragma unroll
      for (int c = 0; c < 3; c++){
        size_t vr = (size_t)((n0 + n)*3 + c)*F + f;
        v[vr] = v[vr] + dv[vr] + avv * b2f(Uv_s[(3*n + c)*136 + f]);
      }
    }
  }
}

// ---------------------------------------------------------------- output head + global sum
__global__ __launch_bounds__(256) void k_out(const float* __restrict__ x,
                                             const float* __restrict__ Wo1, const float* __restrict__ bo1,
                                             const float* __restrict__ Wo2, const float* __restrict__ bo2,
                                             float* __restrict__ out){
  __shared__ float xl[8][F];
  __shared__ float hl[8][F];
  __shared__ float er[8];
  int t = threadIdx.x; int n0 = blockIdx.x * 8;
  #pragma unroll
  for (int i = 0; i < 4; i++){ int idx = t + 256*i; ((float*)xl)[idx] = x[(size_t)n0*F + idx]; }
  __syncthreads();
  { int g = t & 127, grp = t >> 7;
    float acc[4];
    #pragma unroll
    for (int n = 0; n < 4; n++) acc[n] = bo1[g];
    for (int k = 0; k < F; k++){
      float w = Wo1[k*F + g];
      #pragma unroll
      for (int n = 0; n < 4; n++) acc[n] += xl[grp*4+n][k] * w;
    }
    #pragma unroll
    for (int n = 0; n < 4; n++) hl[grp*4+n][g] = silu_f(acc[n]);
  }
  __syncthreads();
  { int r = t >> 5, lq = t & 31;
    float s = 0.f;
    #pragma unroll
    for (int i = 0; i < 4; i++) s += hl[r][lq + 32*i] * Wo2[lq + 32*i];
    #pragma unroll
    for (int m = 16; m >= 1; m >>= 1) s += __shfl_xor(s, m, 64);
    if (lq == 0) er[r] = s + bo2[0];
  }
  __syncthreads();
  if (t == 0){
    float s = 0.f;
    #pragma unroll
    for (int r = 0; r < 8; r++) s += er[r];
    unsafeAtomicAdd(out, s);
  }
}

// ----------------------------------------------------------------
extern "C" void kernel_launch(void* const* d_in, const int* in_sizes, int n_in,
                              void* d_out, int out_size, void* d_ws, size_t ws_size,
                              hipStream_t stream){
  const float* pos     = (const float*)d_in[0];
  const int*   z       = (const int*)  d_in[1];
  const int*   ei      = (const int*)  d_in[2];
  const float* z_embed = (const float*)d_in[3];
  const float* Wrbf    = (const float*)d_in[4];
  const float* brbf    = (const float*)d_in[5];
  const float* ln_g    = (const float*)d_in[6];
  const float* ln_b    = (const float*)d_in[7];
  const float* Wm1     = (const float*)d_in[8];
  const float* bm1     = (const float*)d_in[9];
  const float* Wm2     = (const float*)d_in[10];
  const float* bm2     = (const float*)d_in[11];
  const float* Uw      = (const float*)d_in[12];
  const float* Vw      = (const float*)d_in[13];
  const float* ln2_g   = (const float*)d_in[14];
  const float* ln2_b   = (const float*)d_in[15];
  const float* Wu1     = (const float*)d_in[16];
  const float* bu1     = (const float*)d_in[17];
  const float* Wu2     = (const float*)d_in[18];
  const float* bu2     = (const float*)d_in[19];
  const float* Wo1     = (const float*)d_in[20];
  const float* bo1     = (const float*)d_in[21];
  const float* Wo2     = (const float*)d_in[22];
  const float* bo2     = (const float*)d_in[23];

  float* ws = (float*)d_ws;
  size_t o = 0;
  float* x     = ws + o; o += (size_t)N_ATOM * F;
  float* v     = ws + o; o += (size_t)N_ATOM * 3 * F;
  float* dv    = ws + o; o += (size_t)N_ATOM * 3 * F;
  float* phi   = ws + o; o += (size_t)N_ATOM * 3 * F;
  float* rhs   = ws + o; o += (size_t)NEDGE * 3;
  float* rbfs  = ws + o; o += (size_t)NEDGE * NB;
  float* fcs   = ws + o; o += (size_t)NEDGE;
  int*   rowptr= (int*)(ws + o); o += N_ATOM + 16;
  int*   srcs  = (int*)(ws + o); o += NEDGE;
  short* wt    = (short*)(ws + o); o += 270336 + 8;   // 540672 bf16 weights
  // transient CSR-build arrays alias the dv region (dv first written in
  // k_edge_g, strictly after k_slot/k_geo complete)
  int* deg    = (int*)dv;
  int* cursor = deg + 10240;
  int* slot   = cursor + 10240;

  short* wm1t = wt;
  short* wm2t = wt + 49152;
  short* uwt  = wt + 196608;
  short* vwt  = wt + 245760;
  short* wu1t = wt + 294912;
  short* wu2t = wt + 393216;

  hipMemsetAsync(d_out, 0, sizeof(float), stream);
  hipMemsetAsync(deg, 0, N_ATOM * sizeof(int), stream);
  k_prep<<<2112, 256, 0, stream>>>(Wm1, Wm2, Uw, Vw, Wu1, Wu2, wt);
  k_hist<<<NEDGE/256, 256, 0, stream>>>(ei, deg);
  k_scan<<<1, 1024, 0, stream>>>(deg, rowptr, cursor);
  k_slot<<<NEDGE/256, 256, 0, stream>>>(ei, cursor, slot);
  k_geo <<<NEDGE/256, 256, 0, stream>>>(pos, ei, slot, srcs, rhs, rbfs, fcs);
  k_init<<<(N_ATOM*3*F + 255)/256, 256, 0, stream>>>(z_embed, z, x, v);

  for (int b = 0; b < NBLK; b++){
    k_node_phi<<<N_ATOM/16, 256, 0, stream>>>(x, phi,
        ln_g + b*F, ln_b + b*F, wm1t + b*16384, bm1 + b*F,
        wm2t + b*49152, bm2 + b*F3);
    k_edge_g<<<N_ATOM/4, 256, 0, stream>>>(rowptr, srcs, rbfs, rhs, fcs,
        phi, v, Wrbf + (size_t)b*NB*F3, brbf + b*F3, x, dv);
    k_node_upd<<<N_ATOM/16, 256, 0, stream>>>(x, v, dv,
        uwt + b*16384, vwt + b*16384,
        ln2_g + b*F, ln2_b + b*F,
        wu1t + b*32768, bu1 + b*F,
        wu2t + b*49152, bu2 + b*F3);
  }
  k_out<<<N_ATOM/8, 256, 0, stream>>>(x, Wo1, bo1, Wo2, bo2, (float*)d_out);
}